// Round 4
// baseline (305.435 us; speedup 1.0000x reference)
//
#include <hip/hip_runtime.h>

// Problem constants (from reference): B=16, S=4096, D=256, MAXDUR=8
#define BATCH 16
#define SEQ   4096
#define DIM   256

#define GPB   512                        // expand waves per batch
#define EXP_BLOCKS (BATCH * GPB / 4)     // 2048 blocks, 4 waves each

typedef float f32x4 __attribute__((ext_vector_type(4)));

// ---------------------------------------------------------------------------
// Kernel A: per-batch inclusive scan of durations -> csum[B*S], totals[B]
// One block per batch; 1024 threads * 4 elements = 4096.  (R1 version)
// ---------------------------------------------------------------------------
__global__ __launch_bounds__(1024) void scan_kernel(const int* __restrict__ dims,
                                                    int* __restrict__ csum,
                                                    int* __restrict__ totals) {
    __shared__ int wsum[16];
    const int b    = blockIdx.x;
    const int tid  = threadIdx.x;      // 0..1023
    const int lane = tid & 63;
    const int wave = tid >> 6;         // 0..15

    const int4 dv = ((const int4*)(dims + b * SEQ))[tid];
    const int p0 = dv.x;
    const int p1 = p0 + dv.y;
    const int p2 = p1 + dv.z;
    const int p3 = p2 + dv.w;          // thread-local inclusive sums
    int v = p3;

    #pragma unroll
    for (int off = 1; off < 64; off <<= 1) {
        int n = __shfl_up(v, off, 64);
        if (lane >= off) v += n;
    }
    if (lane == 63) wsum[wave] = v;
    __syncthreads();

    if (tid == 0) {
        int run = 0;
        #pragma unroll
        for (int i = 0; i < 16; ++i) { int t = wsum[i]; wsum[i] = run; run += t; }
        totals[b] = run;
    }
    __syncthreads();

    const int excl = wsum[wave] + (v - p3);
    int4 o;
    o.x = excl + p0; o.y = excl + p1; o.z = excl + p2; o.w = excl + p3;
    ((int4*)(csum + b * SEQ))[tid] = o;    // cached: consumed right after
}

// ---------------------------------------------------------------------------
// Kernel B: persistent monotonic-walk expand.
// 512 waves per batch; wave q owns output rows [q*span, min((q+1)*span, T)).
// One wave-uniform binary search locates the starting source row; then the
// wave walks forward: current x row held in 4 VGPRs, stored to consecutive
// output rows until its csum boundary. The NEXT nonzero row's 1KB load is
// issued BEFORE draining the current row's stores (depth-1 pipeline), so the
// sequential store stream never stalls on a load. Tail zeros emitted inline
// by the same stream (no separate tail pass).
//   - write pattern: ~29KB strictly sequential per wave == fill's pattern
//     (fillBufferAligned measured 6.4 TB/s on this buffer in this window)
//   - x rows read once per touching wave (~59MB + ~8MB boundary duplicates)
//   - R1 lesson kept: stores CACHED, x loads nontemporal
// ---------------------------------------------------------------------------
__global__ __launch_bounds__(256) void expand_persist(const float* __restrict__ x,
                                                      const int* __restrict__ csum,
                                                      const int* __restrict__ totals,
                                                      float* __restrict__ out,
                                                      int T) {
    const int lane = threadIdx.x & 63;
    const int gw   = blockIdx.x * 4 + (threadIdx.x >> 6);   // global wave id
    const int b    = gw >> 9;                               // / GPB
    const int q    = gw & (GPB - 1);
    const int span = (T + GPB - 1) / GPB;

    int t = q * span;
    const int tend = min(t + span, T);
    if (t >= tend) return;

    const int total = totals[b];
    const int* __restrict__ cs   = csum + b * SEQ;
    const f32x4* __restrict__ xb = (const f32x4*)x + (size_t)b * SEQ * (DIM / 4);
    f32x4* __restrict__ ob       = (f32x4*)out + (size_t)b * T * (DIM / 4) + lane;

    if (t < total) {
        // binary search: first s with cs[s] > t  (that row has cnt>0 by construction)
        int lo = 0, hi = SEQ;
        while (lo < hi) {
            const int mid = (lo + hi) >> 1;
            if (cs[mid] <= t) lo = mid + 1; else hi = mid;
        }
        int   s_cur = lo;
        int   e_cur = cs[s_cur];
        f32x4 r_cur = __builtin_nontemporal_load(xb + (size_t)s_cur * (DIM / 4) + lane);

        while (true) {
            // find & issue load of next nonzero row BEFORE draining stores
            int s_nxt = s_cur + 1;
            int e_nxt = e_cur;
            while (s_nxt < SEQ) {
                const int c = cs[s_nxt];
                if (c > e_cur) { e_nxt = c; break; }
                ++s_nxt;                               // skip cnt==0 rows
            }
            const bool have = (s_nxt < SEQ);
            f32x4 r_nxt;
            if (have)
                r_nxt = __builtin_nontemporal_load(xb + (size_t)s_nxt * (DIM / 4) + lane);

            // drain current row's replicas: sequential 1KB wave stores
            const int lim = min(e_cur, tend);
            for (; t < lim; ++t) ob[(size_t)t * (DIM / 4)] = r_cur;

            if (t >= tend) return;
            if (!have) break;                          // rest of span is tail zeros
            s_cur = s_nxt; e_cur = e_nxt; r_cur = r_nxt;
        }
    }

    // tail: rows [max(t,total), tend) are zeros — same sequential stream
    const f32x4 z = {0.f, 0.f, 0.f, 0.f};
    for (; t < tend; ++t) ob[(size_t)t * (DIM / 4)] = z;
}

extern "C" void kernel_launch(void* const* d_in, const int* in_sizes, int n_in,
                              void* d_out, int out_size, void* d_ws, size_t ws_size,
                              hipStream_t stream) {
    const float* x    = (const float*)d_in[0];   // [B,S,D] float32
    const int*   dims = (const int*)d_in[1];     // [B,S,1] int32
    float*       out  = (float*)d_out;           // [B,T,D] float32

    const int T = out_size / (BATCH * DIM);      // padded output length (as R0-R2)

    int* totals = (int*)d_ws;                    // 64 ints (256B, keeps alignment)
    int* csum   = totals + 64;                   // B*S ints

    scan_kernel<<<BATCH, 1024, 0, stream>>>(dims, csum, totals);
    expand_persist<<<EXP_BLOCKS, 256, 0, stream>>>(x, csum, totals, out, T);
}

// Round 5
// 286.562 us; speedup vs baseline: 1.0659x; 1.0659x over previous
//
#include <hip/hip_runtime.h>

// Problem constants (from reference): B=16, S=4096, D=256, MAXDUR=8
#define BATCH 16
#define SEQ   4096
#define DIM   256

#define SCATTER_BLOCKS (BATCH * SEQ / 4)   // 4 waves/block, 1 wave per source row
#define TAILC 128                          // tail-zero blocks per batch

// native clang vector type — accepted by __builtin_nontemporal_{load,store}
typedef float f32x4 __attribute__((ext_vector_type(4)));

// ---------------------------------------------------------------------------
// Kernel A: per-batch inclusive scan of durations -> csum[B*S], totals[B]
// One block per batch; 1024 threads * 4 elements = 4096.
// ---------------------------------------------------------------------------
__global__ __launch_bounds__(1024) void scan_kernel(const int* __restrict__ dims,
                                                    int* __restrict__ csum,
                                                    int* __restrict__ totals) {
    __shared__ int wsum[16];
    const int b    = blockIdx.x;
    const int tid  = threadIdx.x;      // 0..1023
    const int lane = tid & 63;
    const int wave = tid >> 6;         // 0..15

    // 4 consecutive durations per thread (int4, 16B aligned)
    const int4 dv = ((const int4*)(dims + b * SEQ))[tid];
    const int p0 = dv.x;
    const int p1 = p0 + dv.y;
    const int p2 = p1 + dv.z;
    const int p3 = p2 + dv.w;          // thread-local inclusive sums
    int v = p3;                        // thread total

    // wave-level inclusive scan of thread totals (64 lanes)
    #pragma unroll
    for (int off = 1; off < 64; off <<= 1) {
        int n = __shfl_up(v, off, 64);
        if (lane >= off) v += n;
    }
    if (lane == 63) wsum[wave] = v;    // wave total
    __syncthreads();

    if (tid == 0) {                    // serial exclusive scan over 16 wave totals
        int run = 0;
        #pragma unroll
        for (int i = 0; i < 16; ++i) { int t = wsum[i]; wsum[i] = run; run += t; }
        totals[b] = run;               // full batch total
    }
    __syncthreads();

    const int excl = wsum[wave] + (v - p3);   // block-exclusive prefix of this thread
    int4 o;
    o.x = excl + p0; o.y = excl + p1; o.z = excl + p2; o.w = excl + p3;
    // cached store (NOT nontemporal): consumed by expand_kernel right after
    ((int4*)(csum + b * SEQ))[tid] = o;
}

// ---------------------------------------------------------------------------
// Kernel B: scatter-expand + tail zero-fill.  (R1 exact — session best 274.7us)
// Blocks [0, SCATTER_BLOCKS): one wave per source row (b,s). Reads the
//   256-float row once (f32x4/lane = one 1KB wave load) and stores it cnt
//   times to consecutive output rows as 7 INDEPENDENT predicated cached
//   stores (cnt wave-uniform -> s_cbranch).
// Blocks [SCATTER_BLOCKS, +B*TAILC): zero rows [totals[b], T).
//
// Session evidence (R1-R4):
//  - cached output stores beat nontemporal by 8.5us (L2/MALL aggregation);
//  - thin one-row waves beat fat 4-row waves (+17), uniform gather (+27),
//    and persistent sequential walk (+31): expand is bound by the poison-fill
//    writeback drain, and minimal structure overhead wins.
// ---------------------------------------------------------------------------
__global__ __launch_bounds__(256) void expand_kernel(const float* __restrict__ x,
                                                     const int* __restrict__ csum,
                                                     const int* __restrict__ totals,
                                                     float* __restrict__ out,
                                                     int T) {
    const int lane = threadIdx.x & 63;
    const int wave = threadIdx.x >> 6;

    if (blockIdx.x < SCATTER_BLOCKS) {
        const int wv  = blockIdx.x * 4 + wave;    // global source-row id, 0..B*S-1
        const int b   = wv >> 12;                 // / SEQ
        const int s   = wv & (SEQ - 1);

        int start, end;
        if (s != 0) {                             // one int2 load: {csum[wv-1], csum[wv]}
            const int2 se = *(const int2*)(csum + wv - 1);
            start = se.x; end = se.y;
        } else {
            start = 0;   end = csum[wv];
        }
        const int cnt = end - start;              // 0..7, wave-uniform
        if (cnt <= 0) return;

        const f32x4 row = __builtin_nontemporal_load(
            ((const f32x4*)x) + (size_t)wv * (DIM / 4) + lane);
        f32x4* dst = (f32x4*)out + ((size_t)b * T + start) * (DIM / 4) + lane;

        #pragma unroll
        for (int j = 0; j < 7; ++j) {             // independent predicated stores
            if (j < cnt) dst[j * (DIM / 4)] = row;
        }
        for (int j = 7; j < cnt; ++j)             // safety net if MAXDUR ever > 8
            dst[j * (DIM / 4)] = row;
    } else {
        const int idx   = blockIdx.x - SCATTER_BLOCKS;
        const int b     = idx / TAILC;
        const int chunk = idx % TAILC;
        const int t0    = totals[b];
        const f32x4 z   = {0.f, 0.f, 0.f, 0.f};
        // TAILC blocks * 4 waves stride over tail rows of batch b, 2x unrolled
        for (int t = t0 + chunk * 4 + wave; t < T; t += 2 * TAILC * 4) {
            ((f32x4*)out)[((size_t)b * T + t) * (DIM / 4) + lane] = z;
            const int t2 = t + TAILC * 4;
            if (t2 < T)
                ((f32x4*)out)[((size_t)b * T + t2) * (DIM / 4) + lane] = z;
        }
    }
}

extern "C" void kernel_launch(void* const* d_in, const int* in_sizes, int n_in,
                              void* d_out, int out_size, void* d_ws, size_t ws_size,
                              hipStream_t stream) {
    const float* x    = (const float*)d_in[0];   // [B,S,D] float32
    const int*   dims = (const int*)d_in[1];     // [B,S,1] int32
    float*       out  = (float*)d_out;           // [B,T,D] float32

    const int T = out_size / (BATCH * DIM);      // padded output length

    int* totals = (int*)d_ws;                    // B ints
    int* csum   = totals + 64;                   // 256B offset keeps 16B alignment

    scan_kernel<<<BATCH, 1024, 0, stream>>>(dims, csum, totals);
    expand_kernel<<<SCATTER_BLOCKS + BATCH * TAILC, 256, 0, stream>>>(
        x, csum, totals, out, T);
}